// Round 14
// baseline (267.812 us; speedup 1.0000x reference)
//
#include <hip/hip_runtime.h>
#include <stdint.h>

#define B_ 4
#define L_ 2048
#define D_ 1024
#define H_ 16
#define HD_ 64

typedef __attribute__((ext_vector_type(8))) short short8;
typedef __attribute__((ext_vector_type(4))) float f32x4;

__device__ __forceinline__ unsigned short f2bf(float f) {
  union { float f; unsigned int u; } x; x.f = f;
  unsigned int u = x.u;
  u += 0x7FFFu + ((u >> 16) & 1u);   // round-to-nearest-even
  return (unsigned short)(u >> 16);
}

__device__ __forceinline__ f32x4 zero4() {
  f32x4 z; z[0] = 0.f; z[1] = 0.f; z[2] = 0.f; z[3] = 0.f; return z;
}

// async global->LDS, 16B per lane; LDS dest is wave-uniform base + lane*16
__device__ __forceinline__ void gload_lds16(const unsigned short* gp, unsigned short* lp) {
  __builtin_amdgcn_global_load_lds(
      (const __attribute__((address_space(1))) unsigned int*)(const void*)gp,
      (__attribute__((address_space(3))) unsigned int*)(void*)lp, 16, 0, 0);
}

// ---------------- 4-way fused cast fp32 -> bf16 (weights) ----------------
__global__ __launch_bounds__(256) void cast4_bf16(
    const float* __restrict__ s0, const float* __restrict__ s1,
    const float* __restrict__ s2, const float* __restrict__ s3,
    unsigned short* __restrict__ d0, unsigned short* __restrict__ d1,
    unsigned short* __restrict__ d2, unsigned short* __restrict__ d3, int n) {
  int w = blockIdx.y;
  const float* src = (w == 0) ? s0 : (w == 1) ? s1 : (w == 2) ? s2 : s3;
  unsigned short* dst = (w == 0) ? d0 : (w == 1) ? d1 : (w == 2) ? d2 : d3;
  int stride = gridDim.x * blockDim.x * 4;
  for (int i = (blockIdx.x * blockDim.x + threadIdx.x) * 4; i < n; i += stride) {
    float4 f = *(const float4*)(src + i);
    uint2 o;
    o.x = (unsigned int)f2bf(f.x) | ((unsigned int)f2bf(f.y) << 16);
    o.y = (unsigned int)f2bf(f.z) | ((unsigned int)f2bf(f.w) << 16);
    *(uint2*)(dst + i) = o;
  }
}

// ---------------- mask -> per-(q-tile,k-tile) wave-uniform 64-bit words -------
__global__ __launch_bounds__(256) void mask_pack2(const int* __restrict__ m,
                                                  unsigned long long* __restrict__ words) {
  int wid = blockIdx.x * 4 + (threadIdx.x >> 6);   // 0..4095 = qt*32 + kt
  int lane = threadIdx.x & 63;
  int qt = wid >> 5, kt = wid & 31;
  int q = qt * 16 + (lane & 15);
  int g = lane >> 4;
  #pragma unroll
  for (int w = 0; w < 16; ++w) {
    int nt = w >> 2, r = w & 3;
    int key = kt * 64 + nt * 16 + g * 4 + r;
    unsigned long long bal = __ballot(m[(size_t)q * L_ + key] != 0);
    if (lane == 0) words[((size_t)qt * 32 + kt) * 16 + w] = bal;
  }
}

// ---------------- fused q/k/v projection GEMM (z selects), BK=64 --------------
// Proven R9 inner loop (fp32 A reg-staged into swizzled LDS, B via gload_lds).
// bz<2: MODE-1 epilogue (bf16 row-major, scaled). bz==2: MODE-2 per-head
// transpose epilogue; Tsh aliases the dead As/Bs region (Sh), guarded by the
// epilogue's leading __syncthreads. LDS stays 32 KB -> 1536 blocks co-resident.
__global__ __launch_bounds__(256) void gemm_proj3(
    const float* __restrict__ Aq, const float* __restrict__ Ak, const float* __restrict__ Avv,
    const unsigned short* __restrict__ Bq, const unsigned short* __restrict__ Bk,
    const unsigned short* __restrict__ Bv,
    const float* __restrict__ bqv, const float* __restrict__ bkv, const float* __restrict__ bvv,
    unsigned short* __restrict__ Cq, unsigned short* __restrict__ Ck,
    unsigned short* __restrict__ Cv,
    float qscale, int K)
{
  __shared__ __align__(16) unsigned short Sh[2 * 128 * 64];
  unsigned short* As = Sh;
  unsigned short* Bs = Sh + 128 * 64;
  const int t = threadIdx.x;
  const int lane = t & 63;
  const int wave = t >> 6;
  const int g = lane >> 4, cl = lane & 15;
  const int wm = wave >> 1, wn = wave & 1;
  const int bz = blockIdx.z;
  const int m0 = blockIdx.x * 128, n0 = blockIdx.y * 128;

  const float* Af = (bz == 0) ? Aq : (bz == 1) ? Ak : Avv;
  const unsigned short* Bw = (bz == 0) ? Bq : (bz == 1) ? Bk : Bv;
  const float* bias = (bz == 0) ? bqv : (bz == 1) ? bkv : bvv;
  const float scale = (bz == 0) ? qscale : 1.0f;

  f32x4 acc[4][4];
  #pragma unroll
  for (int i = 0; i < 4; ++i)
    #pragma unroll
    for (int j = 0; j < 4; ++j) acc[i][j] = zero4();

  for (int k0 = 0; k0 < K; k0 += 64) {
    __syncthreads();
    #pragma unroll
    for (int i = 0; i < 4; ++i) {
      int c = i * 256 + t;            // 0..1023: row = c>>3, chunk = c&7
      int row = c >> 3, cc = c & 7;
      int scc = ((cc ^ (row & 7)) << 3);
      const float* ap = Af + (size_t)(m0 + row) * K + k0 + cc * 8;
      float4 f0 = *(const float4*)ap;
      float4 f1 = *(const float4*)(ap + 4);
      unsigned int u0, u1, u2, u3;
      asm("v_cvt_pk_bf16_f32 %0, %1, %2" : "=v"(u0) : "v"(f0.x), "v"(f0.y));
      asm("v_cvt_pk_bf16_f32 %0, %1, %2" : "=v"(u1) : "v"(f0.z), "v"(f0.w));
      asm("v_cvt_pk_bf16_f32 %0, %1, %2" : "=v"(u2) : "v"(f1.x), "v"(f1.y));
      asm("v_cvt_pk_bf16_f32 %0, %1, %2" : "=v"(u3) : "v"(f1.z), "v"(f1.w));
      uint4 u; u.x = u0; u.y = u1; u.z = u2; u.w = u3;
      *(uint4*)&As[row * 64 + scc] = u;
      gload_lds16(Bw + (size_t)(n0 + row) * K + k0 + scc, &Bs[c << 3]);
    }
    __syncthreads();
    #pragma unroll
    for (int kk = 0; kk < 2; ++kk) {
      short8 af[4], bf[4];
      #pragma unroll
      for (int mt = 0; mt < 4; ++mt)
        af[mt] = *(const short8*)&As[(wm * 64 + mt * 16 + cl) * 64
                                     + ((kk * 32 + g * 8) ^ ((cl & 7) << 3))];
      #pragma unroll
      for (int nt = 0; nt < 4; ++nt)
        bf[nt] = *(const short8*)&Bs[(wn * 64 + nt * 16 + cl) * 64
                                     + ((kk * 32 + g * 8) ^ ((cl & 7) << 3))];
      #pragma unroll
      for (int mt = 0; mt < 4; ++mt)
        #pragma unroll
        for (int nt = 0; nt < 4; ++nt)
          acc[mt][nt] = __builtin_amdgcn_mfma_f32_16x16x32_bf16(af[mt], bf[nt], acc[mt][nt], 0, 0, 0);
    }
  }

  if (bz < 2) {
    unsigned short* Cp = (bz == 0) ? Cq : Ck;
    #pragma unroll
    for (int nt = 0; nt < 4; ++nt) {
      int col = n0 + wn * 64 + nt * 16 + cl;
      float bv = bias[col];
      #pragma unroll
      for (int mt = 0; mt < 4; ++mt) {
        #pragma unroll
        for (int r = 0; r < 4; ++r) {
          int row = m0 + wm * 64 + mt * 16 + g * 4 + r;
          Cp[(size_t)row * D_ + col] = f2bf((acc[mt][nt][r] + bv) * scale);
        }
      }
    }
  } else {
    // per-head transpose epilogue; Tsh aliases Sh (As/Bs dead after K-loop)
    unsigned short* Tsh = Sh;
    const int b = m0 >> 11;   // m0 / L_
    #pragma unroll 1
    for (int half = 0; half < 2; ++half) {
      __syncthreads();
      if (wn == half) {
        #pragma unroll
        for (int nt = 0; nt < 4; ++nt) {
          float bv = bias[n0 + wn * 64 + nt * 16 + cl];
          #pragma unroll
          for (int mt = 0; mt < 4; ++mt) {
            float v0 = acc[mt][nt][0] + bv, v1 = acc[mt][nt][1] + bv;
            float v2 = acc[mt][nt][2] + bv, v3 = acc[mt][nt][3] + bv;
            unsigned int lo, hi;
            asm("v_cvt_pk_bf16_f32 %0, %1, %2" : "=v"(lo) : "v"(v0), "v"(v1));
            asm("v_cvt_pk_bf16_f32 %0, %1, %2" : "=v"(hi) : "v"(v2), "v"(v3));
            uint2 u; u.x = lo; u.y = hi;
            *(uint2*)&Tsh[(nt * 16 + cl) * 136 + wm * 64 + mt * 16 + g * 4] = u;
          }
        }
      }
      __syncthreads();
      #pragma unroll
      for (int p = 0; p < 4; ++p) {
        int chunk = p * 256 + t;
        int c = chunk >> 4, li = (chunk & 15) * 8;
        int colg = n0 + half * 64 + c;
        int hh = colg >> 6, d = colg & 63;
        short8 vv = *(const short8*)&Tsh[c * 136 + li];
        *(short8*)(Cv + (((size_t)(b * 16 + hh)) << 17)
                   + (size_t)d * L_ + (m0 & (L_ - 1)) + li) = vv;
      }
    }
  }
}

// ---------------- final GEMM: d_out = ctx * Wo^T + bo (f32 out, R9 proven) ----
__global__ __launch_bounds__(256) void gemm_out(
    const unsigned short* __restrict__ A,
    const unsigned short* __restrict__ Bw,
    const float* __restrict__ bias,
    float* __restrict__ Cp, int K)
{
  __shared__ __align__(16) unsigned short As[128 * 64];
  __shared__ __align__(16) unsigned short Bs[128 * 64];
  const int t = threadIdx.x;
  const int lane = t & 63;
  const int wave = t >> 6;
  const int g = lane >> 4, cl = lane & 15;
  const int wm = wave >> 1, wn = wave & 1;
  const int m0 = blockIdx.x * 128, n0 = blockIdx.y * 128;

  f32x4 acc[4][4];
  #pragma unroll
  for (int i = 0; i < 4; ++i)
    #pragma unroll
    for (int j = 0; j < 4; ++j) acc[i][j] = zero4();

  for (int k0 = 0; k0 < K; k0 += 64) {
    __syncthreads();
    #pragma unroll
    for (int i = 0; i < 4; ++i) {
      int c = i * 256 + t;
      int row = c >> 3, cc = c & 7;
      int scc = ((cc ^ (row & 7)) << 3);
      gload_lds16(A + (size_t)(m0 + row) * K + k0 + scc, &As[c << 3]);
      gload_lds16(Bw + (size_t)(n0 + row) * K + k0 + scc, &Bs[c << 3]);
    }
    __syncthreads();
    #pragma unroll
    for (int kk = 0; kk < 2; ++kk) {
      short8 af[4], bf[4];
      #pragma unroll
      for (int mt = 0; mt < 4; ++mt)
        af[mt] = *(const short8*)&As[(wm * 64 + mt * 16 + cl) * 64
                                     + ((kk * 32 + g * 8) ^ ((cl & 7) << 3))];
      #pragma unroll
      for (int nt = 0; nt < 4; ++nt)
        bf[nt] = *(const short8*)&Bs[(wn * 64 + nt * 16 + cl) * 64
                                     + ((kk * 32 + g * 8) ^ ((cl & 7) << 3))];
      #pragma unroll
      for (int mt = 0; mt < 4; ++mt)
        #pragma unroll
        for (int nt = 0; nt < 4; ++nt)
          acc[mt][nt] = __builtin_amdgcn_mfma_f32_16x16x32_bf16(af[mt], bf[nt], acc[mt][nt], 0, 0, 0);
    }
  }

  #pragma unroll
  for (int nt = 0; nt < 4; ++nt) {
    int col = n0 + wn * 64 + nt * 16 + cl;
    float bv = bias[col];
    #pragma unroll
    for (int mt = 0; mt < 4; ++mt) {
      #pragma unroll
      for (int r = 0; r < 4; ++r) {
        int row = m0 + wm * 64 + mt * 16 + g * 4 + r;
        Cp[(size_t)row * D_ + col] = acc[mt][nt][r] + bv;
      }
    }
  }
}

// ---------------- flash attention (R13 proven body + head-affine XCD swizzle) -
// 1D grid 2048, decode: r=d&7, x=(d>>3)&31, bh=r+8*(d>>8)  (bijective).
// All 32 q-blocks of a head map to one XCD -> KV stays in that XCD's L2.
__global__ __launch_bounds__(256) void flash_attn(
    const unsigned short* __restrict__ qw,   // pre-scaled by log2e/8
    const unsigned short* __restrict__ kw,
    const unsigned short* __restrict__ vt,   // [B*H][64][L]
    const unsigned long long* __restrict__ mwords,
    unsigned short* __restrict__ ctx)
{
  __shared__ __align__(16) unsigned short Ksh[2][64 * 64];  // [key][d], swizzled
  __shared__ __align__(16) unsigned short Vsh[2][64 * 64];  // [d][key], swizzled
  __shared__ __align__(16) unsigned short Psh[64 * 64];     // 16 rows/wave, XOR-swz

  const int t = threadIdx.x;
  const int lane = t & 63;
  const int wave = t >> 6;
  const int g = lane >> 4, cl = lane & 15;

  // head-affine bijective XCD swizzle
  const int d0i = blockIdx.x;
  const int xq = (d0i >> 3) & 31;                 // q-block 0..31
  const int bh = (d0i & 7) + ((d0i >> 8) << 3);   // head 0..63
  const int b = bh >> 4, h = bh & 15;
  const int qb = xq * 64 + wave * 16;

  const size_t baseq = (size_t)b * L_ * D_ + (size_t)h * HD_;
  const size_t basev = (size_t)bh * HD_ * L_;

  // wave-uniform mask-word row pointer
  const int qtu = __builtin_amdgcn_readfirstlane(xq * 4 + wave);
  const unsigned long long* __restrict__ mrow = mwords + (size_t)qtu * (32 * 16);

  // hoisted per-lane staging bases (tile kt adds kt*64*D_ for K, kt*64 for V)
  const int c0 = t, c1 = 256 + t;
  const int r0 = c0 >> 3, r1 = c1 >> 3;
  const int s0 = ((c0 & 7) ^ (r0 & 7)) << 3, s1 = ((c1 & 7) ^ (r1 & 7)) << 3;
  const unsigned short* kg0 = kw + baseq + (size_t)r0 * D_ + s0;
  const unsigned short* kg1 = kw + baseq + (size_t)r1 * D_ + s1;
  const unsigned short* vg0 = vt + basev + (size_t)r0 * L_ + s0;
  const unsigned short* vg1 = vt + basev + (size_t)r1 * L_ + s1;

#define STAGE_KV(bufi, kti)                                                     \
  {                                                                             \
    const size_t ko = (size_t)(kti) * (64 * D_);                                \
    const int vo = (kti) * 64;                                                  \
    gload_lds16(kg0 + ko, &Ksh[bufi][c0 << 3]);                                 \
    gload_lds16(vg0 + vo, &Vsh[bufi][c0 << 3]);                                 \
    gload_lds16(kg1 + ko, &Ksh[bufi][c1 << 3]);                                 \
    gload_lds16(vg1 + vo, &Vsh[bufi][c1 << 3]);                                 \
  }

  // Q fragment (B-frag of S^T): row=q=cl, k = d = kk*32 + g*8 + j
  short8 bq[2];
  #pragma unroll
  for (int kk = 0; kk < 2; ++kk)
    bq[kk] = *(const short8*)(qw + baseq + (size_t)(qb + cl) * D_ + kk * 32 + g * 8);

  // ones B-fragment for MFMA row-sums (bf16 1.0 = 0x3F80)
  short8 ones;
  #pragma unroll
  for (int i = 0; i < 8; ++i) ones[i] = (short)0x3F80;

  f32x4 oacc[4], lsum;
  #pragma unroll
  for (int dt = 0; dt < 4; ++dt) oacc[dt] = zero4();
  lsum = zero4();
  float ninf = -1e30f;                    // VGPR constant for cndmask

  STAGE_KV(0, 0);
  __syncthreads();

  int buf = 0;
  for (int kt = 0; kt < L_ / 64; ++kt) {
    // wave-uniform mask words for this tile (contiguous 128 B -> s_load)
    unsigned long long Mw[16];
    #pragma unroll
    for (int w = 0; w < 16; ++w) Mw[w] = mrow[kt * 16 + w];

    if (kt + 1 < L_ / 64) STAGE_KV(buf ^ 1, kt + 1);

    // S^T - 16 = K Q^T + (-16) : sc[nt] holds keys nt*16+g*4+r for q=cl
    f32x4 sc[4];
    #pragma unroll
    for (int nt = 0; nt < 4; ++nt) {
      sc[nt][0] = -16.f; sc[nt][1] = -16.f; sc[nt][2] = -16.f; sc[nt][3] = -16.f;
    }
    __builtin_amdgcn_s_setprio(1);
    #pragma unroll
    for (int kk = 0; kk < 2; ++kk) {
      #pragma unroll
      for (int nt = 0; nt < 4; ++nt) {
        short8 ak = *(const short8*)&Ksh[buf][(nt * 16 + cl) * 64
                                             + ((kk * 32 + g * 8) ^ ((cl & 7) << 3))];
        sc[nt] = __builtin_amdgcn_mfma_f32_16x16x32_bf16(ak, bq[kk], sc[nt], 0, 0, 0);
      }
    }
    __builtin_amdgcn_s_setprio(0);

    // mask (one cndmask/elem) then p = exp2(s - 16); masked -> exp2(-1e30) = 0
    float p[4][4];
    #pragma unroll
    for (int nt = 0; nt < 4; ++nt)
      #pragma unroll
      for (int r = 0; r < 4; ++r) {
        float sv;
        asm("v_cndmask_b32 %0, %1, %2, %3"
            : "=v"(sv)
            : "v"(sc[nt][r]), "v"(ninf), "s"(Mw[nt * 4 + r]));
        p[nt][r] = __builtin_amdgcn_exp2f(sv);
      }

    // P -> LDS (bf16, b64 per nt); wave-private rows, XOR-swizzled
    #pragma unroll
    for (int nt = 0; nt < 4; ++nt) {
      unsigned int lo, hi;
      asm("v_cvt_pk_bf16_f32 %0, %1, %2" : "=v"(lo) : "v"(p[nt][0]), "v"(p[nt][1]));
      asm("v_cvt_pk_bf16_f32 %0, %1, %2" : "=v"(hi) : "v"(p[nt][2]), "v"(p[nt][3]));
      uint2 u; u.x = lo; u.y = hi;
      *(uint2*)&Psh[(((wave * 16 + cl) * 64) + nt * 16 + g * 4) ^ ((cl & 7) << 3)] = u;
    }

    // O += P V, lsum += P * ones : A = P (rows q), B = V^T (rows d) / ones
    short8 pa[2];
    #pragma unroll
    for (int kk = 0; kk < 2; ++kk)
      pa[kk] = *(const short8*)&Psh[(((wave * 16 + cl) * 64) + kk * 32 + g * 8)
                                    ^ ((cl & 7) << 3)];
    __builtin_amdgcn_s_setprio(1);
    #pragma unroll
    for (int kk = 0; kk < 2; ++kk) {
      #pragma unroll
      for (int dt = 0; dt < 4; ++dt) {
        short8 bv = *(const short8*)&Vsh[buf][(dt * 16 + cl) * 64
                                             + ((kk * 32 + g * 8) ^ ((cl & 7) << 3))];
        oacc[dt] = __builtin_amdgcn_mfma_f32_16x16x32_bf16(pa[kk], bv, oacc[dt], 0, 0, 0);
      }
      lsum = __builtin_amdgcn_mfma_f32_16x16x32_bf16(pa[kk], ones, lsum, 0, 0, 0);
    }
    __builtin_amdgcn_s_setprio(0);

    __syncthreads();   // drains vmcnt (next tile staged) + protects buffer reuse
    buf ^= 1;
  }

  // epilogue: lsum[r] is the row-sum for q = qb + g*4 + r (col-replicated)
  #pragma unroll
  for (int r = 0; r < 4; ++r) {
    float iv = __builtin_amdgcn_rcpf(lsum[r]);
    #pragma unroll
    for (int dt = 0; dt < 4; ++dt)
      ctx[baseq + (size_t)(qb + g * 4 + r) * D_ + dt * 16 + cl] = f2bf(oacc[dt][r] * iv);
  }
#undef STAGE_KV
}

// ---------------- launch ----------------
extern "C" void kernel_launch(void* const* d_in, const int* in_sizes, int n_in,
                              void* d_out, int out_size, void* d_ws, size_t ws_size,
                              hipStream_t stream) {
  (void)in_sizes; (void)n_in; (void)out_size; (void)ws_size;
  const float* q    = (const float*)d_in[0];
  const float* k    = (const float*)d_in[1];
  const float* v    = (const float*)d_in[2];
  const int*   mask = (const int*)d_in[3];
  const float* Wq   = (const float*)d_in[4];
  const float* bq   = (const float*)d_in[5];
  const float* Wk   = (const float*)d_in[6];
  const float* bk   = (const float*)d_in[7];
  const float* Wv   = (const float*)d_in[8];
  const float* bv   = (const float*)d_in[9];
  const float* Wo   = (const float*)d_in[10];
  const float* bo   = (const float*)d_in[11];

  char* ws = (char*)d_ws;
  const size_t MB = 1024 * 1024;
  unsigned short* Wqb  = (unsigned short*)(ws + 16 * MB);
  unsigned short* Wkb  = (unsigned short*)(ws + 18 * MB);
  unsigned short* Wvb  = (unsigned short*)(ws + 20 * MB);
  unsigned short* Wob  = (unsigned short*)(ws + 22 * MB);
  unsigned short* qwb  = (unsigned short*)(ws + 24 * MB);  // pre-scaled Q proj
  unsigned short* kwb  = (unsigned short*)(ws + 40 * MB);
  unsigned short* vtb  = (unsigned short*)(ws + 56 * MB);  // V^T per head
  unsigned short* ctx  = (unsigned short*)(ws + 72 * MB);
  unsigned long long* mwd = (unsigned long long*)(ws + 88 * MB);  // 512 KB

  const int NW = D_ * D_;

  cast4_bf16<<<dim3(512, 4), 256, 0, stream>>>(Wq, Wk, Wv, Wo, Wqb, Wkb, Wvb, Wob, NW);
  mask_pack2<<<1024, 256, 0, stream>>>(mask, mwd);

  // Q pre-scaled by log2e / sqrt(HD) for log2-domain softmax
  const float QSCALE = 0.125f * 1.44269504088896340736f;

  // fused q+k+v projections (z = 0/1/2)
  gemm_proj3<<<dim3(64, 8, 3), 256, 0, stream>>>(
      q, k, v, Wqb, Wkb, Wvb, bq, bk, bv, qwb, kwb, vtb, QSCALE, D_);

  flash_attn<<<dim3(2048), 256, 0, stream>>>(qwb, kwb, vtb, mwd, ctx);

  gemm_out<<<dim3(64, 8), 256, 0, stream>>>(ctx, Wob, bo, (float*)d_out, D_);
}

// Round 15
// 238.160 us; speedup vs baseline: 1.1245x; 1.1245x over previous
//
#include <hip/hip_runtime.h>
#include <stdint.h>

#define B_ 4
#define L_ 2048
#define D_ 1024
#define H_ 16
#define HD_ 64

typedef __attribute__((ext_vector_type(8))) short short8;
typedef __attribute__((ext_vector_type(4))) float f32x4;

__device__ __forceinline__ unsigned short f2bf(float f) {
  union { float f; unsigned int u; } x; x.f = f;
  unsigned int u = x.u;
  u += 0x7FFFu + ((u >> 16) & 1u);   // round-to-nearest-even
  return (unsigned short)(u >> 16);
}

__device__ __forceinline__ f32x4 zero4() {
  f32x4 z; z[0] = 0.f; z[1] = 0.f; z[2] = 0.f; z[3] = 0.f; return z;
}

// async global->LDS, 16B per lane; LDS dest is wave-uniform base + lane*16
__device__ __forceinline__ void gload_lds16(const unsigned short* gp, unsigned short* lp) {
  __builtin_amdgcn_global_load_lds(
      (const __attribute__((address_space(1))) unsigned int*)(const void*)gp,
      (__attribute__((address_space(3))) unsigned int*)(void*)lp, 16, 0, 0);
}

// ---------------- 4-way fused cast fp32 -> bf16 (weights) ----------------
__global__ __launch_bounds__(256) void cast4_bf16(
    const float* __restrict__ s0, const float* __restrict__ s1,
    const float* __restrict__ s2, const float* __restrict__ s3,
    unsigned short* __restrict__ d0, unsigned short* __restrict__ d1,
    unsigned short* __restrict__ d2, unsigned short* __restrict__ d3, int n) {
  int w = blockIdx.y;
  const float* src = (w == 0) ? s0 : (w == 1) ? s1 : (w == 2) ? s2 : s3;
  unsigned short* dst = (w == 0) ? d0 : (w == 1) ? d1 : (w == 2) ? d2 : d3;
  int stride = gridDim.x * blockDim.x * 4;
  for (int i = (blockIdx.x * blockDim.x + threadIdx.x) * 4; i < n; i += stride) {
    float4 f = *(const float4*)(src + i);
    uint2 o;
    o.x = (unsigned int)f2bf(f.x) | ((unsigned int)f2bf(f.y) << 16);
    o.y = (unsigned int)f2bf(f.z) | ((unsigned int)f2bf(f.w) << 16);
    *(uint2*)(dst + i) = o;
  }
}

// ---------------- mask -> per-(q-tile,k-tile) wave-uniform 64-bit words -------
__global__ __launch_bounds__(256) void mask_pack2(const int* __restrict__ m,
                                                  unsigned long long* __restrict__ words) {
  int wid = blockIdx.x * 4 + (threadIdx.x >> 6);   // 0..4095 = qt*32 + kt
  int lane = threadIdx.x & 63;
  int qt = wid >> 5, kt = wid & 31;
  int q = qt * 16 + (lane & 15);
  int g = lane >> 4;
  #pragma unroll
  for (int w = 0; w < 16; ++w) {
    int nt = w >> 2, r = w & 3;
    int key = kt * 64 + nt * 16 + g * 4 + r;
    unsigned long long bal = __ballot(m[(size_t)q * L_ + key] != 0);
    if (lane == 0) words[((size_t)qt * 32 + kt) * 16 + w] = bal;
  }
}

// ---------------- bf16 GEMM: C = A * Bw^T + bias, BK=64, XOR-swizzled LDS ----
// R13 exact (HW-proven): separate As/Bs shared objects (no-alias guarantee
// keeps global_load_lds async), compile-time MODE/AF32/FUSE2 templates,
// default blockIdx mapping. FUSE2: gridDim.z=2 runs two GEMMs in one dispatch.
template<int MODE, bool AF32, bool FUSE2>
__global__ __launch_bounds__(256) void gemm_bt(
    const void* __restrict__ A0v, const void* __restrict__ A1v,
    const unsigned short* __restrict__ B0w, const unsigned short* __restrict__ B1w,
    const float* __restrict__ bias0, const float* __restrict__ bias1,
    void* __restrict__ C0p, void* __restrict__ C1p,
    float scale0, float scale1, int K)
{
  __shared__ __align__(16) unsigned short As[128 * 64];
  __shared__ __align__(16) unsigned short Bs[128 * 64];
  __shared__ __align__(16) unsigned short Tsh[MODE == 2 ? 64 * 136 : 16];
  const int t = threadIdx.x;
  const int lane = t & 63;
  const int wave = t >> 6;
  const int g = lane >> 4, cl = lane & 15;
  const int wm = wave >> 1, wn = wave & 1;

  const int bx = blockIdx.x;
  const int by = blockIdx.y;
  const int bz = FUSE2 ? blockIdx.z : 0;

  const void* Av = (FUSE2 && bz) ? A1v : A0v;
  const unsigned short* Bw = (FUSE2 && bz) ? B1w : B0w;
  const float* bias = (FUSE2 && bz) ? bias1 : bias0;
  void* Cp = (FUSE2 && bz) ? C1p : C0p;
  const float scale = (FUSE2 && bz) ? scale1 : scale0;

  const int m0 = bx * 128, n0 = by * 128;

  f32x4 acc[4][4];
  #pragma unroll
  for (int i = 0; i < 4; ++i)
    #pragma unroll
    for (int j = 0; j < 4; ++j) acc[i][j] = zero4();

  for (int k0 = 0; k0 < K; k0 += 64) {
    __syncthreads();
    #pragma unroll
    for (int i = 0; i < 4; ++i) {
      int c = i * 256 + t;            // 0..1023: row = c>>3, chunk = c&7
      int row = c >> 3, cc = c & 7;
      int scc = ((cc ^ (row & 7)) << 3);
      if constexpr (AF32) {
        const float* Af = (const float*)Av;
        const float* ap = Af + (size_t)(m0 + row) * K + k0 + cc * 8;
        float4 f0 = *(const float4*)ap;
        float4 f1 = *(const float4*)(ap + 4);
        unsigned int u0, u1, u2, u3;
        asm("v_cvt_pk_bf16_f32 %0, %1, %2" : "=v"(u0) : "v"(f0.x), "v"(f0.y));
        asm("v_cvt_pk_bf16_f32 %0, %1, %2" : "=v"(u1) : "v"(f0.z), "v"(f0.w));
        asm("v_cvt_pk_bf16_f32 %0, %1, %2" : "=v"(u2) : "v"(f1.x), "v"(f1.y));
        asm("v_cvt_pk_bf16_f32 %0, %1, %2" : "=v"(u3) : "v"(f1.z), "v"(f1.w));
        uint4 u; u.x = u0; u.y = u1; u.z = u2; u.w = u3;
        *(uint4*)&As[row * 64 + scc] = u;
      } else {
        gload_lds16((const unsigned short*)Av + (size_t)(m0 + row) * K + k0 + scc,
                    &As[c << 3]);
      }
      gload_lds16(Bw + (size_t)(n0 + row) * K + k0 + scc, &Bs[c << 3]);
    }
    __syncthreads();
    #pragma unroll
    for (int kk = 0; kk < 2; ++kk) {
      short8 af[4], bf[4];
      #pragma unroll
      for (int mt = 0; mt < 4; ++mt)
        af[mt] = *(const short8*)&As[(wm * 64 + mt * 16 + cl) * 64
                                     + ((kk * 32 + g * 8) ^ ((cl & 7) << 3))];
      #pragma unroll
      for (int nt = 0; nt < 4; ++nt)
        bf[nt] = *(const short8*)&Bs[(wn * 64 + nt * 16 + cl) * 64
                                     + ((kk * 32 + g * 8) ^ ((cl & 7) << 3))];
      #pragma unroll
      for (int mt = 0; mt < 4; ++mt)
        #pragma unroll
        for (int nt = 0; nt < 4; ++nt)
          acc[mt][nt] = __builtin_amdgcn_mfma_f32_16x16x32_bf16(af[mt], bf[nt], acc[mt][nt], 0, 0, 0);
    }
  }

  if constexpr (MODE <= 1) {
    #pragma unroll
    for (int nt = 0; nt < 4; ++nt) {
      int col = n0 + wn * 64 + nt * 16 + cl;
      float bv = bias[col];
      #pragma unroll
      for (int mt = 0; mt < 4; ++mt) {
        #pragma unroll
        for (int r = 0; r < 4; ++r) {
          int row = m0 + wm * 64 + mt * 16 + g * 4 + r;
          float val = (acc[mt][nt][r] + bv) * scale;
          if (MODE == 0)
            ((float*)Cp)[(size_t)row * D_ + col] = val;
          else
            ((unsigned short*)Cp)[(size_t)row * D_ + col] = f2bf(val);
        }
      }
    }
  } else {
    // transpose 64-col halves through LDS, write vt[(b*H+h)][d][l] coalesced
    const int b = m0 >> 11;   // m0 / L_
    #pragma unroll 1
    for (int half = 0; half < 2; ++half) {
      __syncthreads();
      if (wn == half) {
        #pragma unroll
        for (int nt = 0; nt < 4; ++nt) {
          float bv = bias[n0 + wn * 64 + nt * 16 + cl];
          #pragma unroll
          for (int mt = 0; mt < 4; ++mt) {
            float v0 = acc[mt][nt][0] + bv, v1 = acc[mt][nt][1] + bv;
            float v2 = acc[mt][nt][2] + bv, v3 = acc[mt][nt][3] + bv;
            unsigned int lo, hi;
            asm("v_cvt_pk_bf16_f32 %0, %1, %2" : "=v"(lo) : "v"(v0), "v"(v1));
            asm("v_cvt_pk_bf16_f32 %0, %1, %2" : "=v"(hi) : "v"(v2), "v"(v3));
            uint2 u; u.x = lo; u.y = hi;
            *(uint2*)&Tsh[(nt * 16 + cl) * 136 + wm * 64 + mt * 16 + g * 4] = u;
          }
        }
      }
      __syncthreads();
      #pragma unroll
      for (int p = 0; p < 4; ++p) {
        int chunk = p * 256 + t;
        int c = chunk >> 4, li = (chunk & 15) * 8;
        int colg = n0 + half * 64 + c;
        int hh = colg >> 6, d = colg & 63;
        short8 vv = *(const short8*)&Tsh[c * 136 + li];
        *(short8*)((unsigned short*)Cp + (((size_t)(b * 16 + hh)) << 17)
                   + (size_t)d * L_ + (m0 & (L_ - 1)) + li) = vv;
      }
    }
  }
}

// ---------------- flash attention (R13 proven body + head-affine XCD swizzle) -
// 1D grid 2048, decode: xq=(d>>3)&31, bh=(d&7)+8*(d>>8)  (bijective).
// All 32 q-blocks of a head map to one XCD -> KV stays in that XCD's L2
// (R14-measured: flash dropped ~119 -> ~85 us with this decode).
__global__ __launch_bounds__(256) void flash_attn(
    const unsigned short* __restrict__ qw,   // pre-scaled by log2e/8
    const unsigned short* __restrict__ kw,
    const unsigned short* __restrict__ vt,   // [B*H][64][L]
    const unsigned long long* __restrict__ mwords,
    unsigned short* __restrict__ ctx)
{
  __shared__ __align__(16) unsigned short Ksh[2][64 * 64];  // [key][d], swizzled
  __shared__ __align__(16) unsigned short Vsh[2][64 * 64];  // [d][key], swizzled
  __shared__ __align__(16) unsigned short Psh[64 * 64];     // 16 rows/wave, XOR-swz

  const int t = threadIdx.x;
  const int lane = t & 63;
  const int wave = t >> 6;
  const int g = lane >> 4, cl = lane & 15;

  // head-affine bijective XCD swizzle
  const int d0i = blockIdx.x;
  const int xq = (d0i >> 3) & 31;                 // q-block 0..31
  const int bh = (d0i & 7) + ((d0i >> 8) << 3);   // head 0..63
  const int b = bh >> 4, h = bh & 15;
  const int qb = xq * 64 + wave * 16;

  const size_t baseq = (size_t)b * L_ * D_ + (size_t)h * HD_;
  const size_t basev = (size_t)bh * HD_ * L_;

  // wave-uniform mask-word row pointer
  const int qtu = __builtin_amdgcn_readfirstlane(xq * 4 + wave);
  const unsigned long long* __restrict__ mrow = mwords + (size_t)qtu * (32 * 16);

  // hoisted per-lane staging bases (tile kt adds kt*64*D_ for K, kt*64 for V)
  const int c0 = t, c1 = 256 + t;
  const int r0 = c0 >> 3, r1 = c1 >> 3;
  const int s0 = ((c0 & 7) ^ (r0 & 7)) << 3, s1 = ((c1 & 7) ^ (r1 & 7)) << 3;
  const unsigned short* kg0 = kw + baseq + (size_t)r0 * D_ + s0;
  const unsigned short* kg1 = kw + baseq + (size_t)r1 * D_ + s1;
  const unsigned short* vg0 = vt + basev + (size_t)r0 * L_ + s0;
  const unsigned short* vg1 = vt + basev + (size_t)r1 * L_ + s1;

#define STAGE_KV(bufi, kti)                                                     \
  {                                                                             \
    const size_t ko = (size_t)(kti) * (64 * D_);                                \
    const int vo = (kti) * 64;                                                  \
    gload_lds16(kg0 + ko, &Ksh[bufi][c0 << 3]);                                 \
    gload_lds16(vg0 + vo, &Vsh[bufi][c0 << 3]);                                 \
    gload_lds16(kg1 + ko, &Ksh[bufi][c1 << 3]);                                 \
    gload_lds16(vg1 + vo, &Vsh[bufi][c1 << 3]);                                 \
  }

  // Q fragment (B-frag of S^T): row=q=cl, k = d = kk*32 + g*8 + j
  short8 bq[2];
  #pragma unroll
  for (int kk = 0; kk < 2; ++kk)
    bq[kk] = *(const short8*)(qw + baseq + (size_t)(qb + cl) * D_ + kk * 32 + g * 8);

  // ones B-fragment for MFMA row-sums (bf16 1.0 = 0x3F80)
  short8 ones;
  #pragma unroll
  for (int i = 0; i < 8; ++i) ones[i] = (short)0x3F80;

  f32x4 oacc[4], lsum;
  #pragma unroll
  for (int dt = 0; dt < 4; ++dt) oacc[dt] = zero4();
  lsum = zero4();
  float ninf = -1e30f;                    // VGPR constant for cndmask

  STAGE_KV(0, 0);
  __syncthreads();

  int buf = 0;
  for (int kt = 0; kt < L_ / 64; ++kt) {
    // wave-uniform mask words for this tile (contiguous 128 B -> s_load)
    unsigned long long Mw[16];
    #pragma unroll
    for (int w = 0; w < 16; ++w) Mw[w] = mrow[kt * 16 + w];

    if (kt + 1 < L_ / 64) STAGE_KV(buf ^ 1, kt + 1);

    // S^T - 16 = K Q^T + (-16) : sc[nt] holds keys nt*16+g*4+r for q=cl
    f32x4 sc[4];
    #pragma unroll
    for (int nt = 0; nt < 4; ++nt) {
      sc[nt][0] = -16.f; sc[nt][1] = -16.f; sc[nt][2] = -16.f; sc[nt][3] = -16.f;
    }
    __builtin_amdgcn_s_setprio(1);
    #pragma unroll
    for (int kk = 0; kk < 2; ++kk) {
      #pragma unroll
      for (int nt = 0; nt < 4; ++nt) {
        short8 ak = *(const short8*)&Ksh[buf][(nt * 16 + cl) * 64
                                             + ((kk * 32 + g * 8) ^ ((cl & 7) << 3))];
        sc[nt] = __builtin_amdgcn_mfma_f32_16x16x32_bf16(ak, bq[kk], sc[nt], 0, 0, 0);
      }
    }
    __builtin_amdgcn_s_setprio(0);

    // mask (one cndmask/elem) then p = exp2(s - 16); masked -> exp2(-1e30) = 0
    float p[4][4];
    #pragma unroll
    for (int nt = 0; nt < 4; ++nt)
      #pragma unroll
      for (int r = 0; r < 4; ++r) {
        float sv;
        asm("v_cndmask_b32 %0, %1, %2, %3"
            : "=v"(sv)
            : "v"(sc[nt][r]), "v"(ninf), "s"(Mw[nt * 4 + r]));
        p[nt][r] = __builtin_amdgcn_exp2f(sv);
      }

    // P -> LDS (bf16, b64 per nt); wave-private rows, XOR-swizzled
    #pragma unroll
    for (int nt = 0; nt < 4; ++nt) {
      unsigned int lo, hi;
      asm("v_cvt_pk_bf16_f32 %0, %1, %2" : "=v"(lo) : "v"(p[nt][0]), "v"(p[nt][1]));
      asm("v_cvt_pk_bf16_f32 %0, %1, %2" : "=v"(hi) : "v"(p[nt][2]), "v"(p[nt][3]));
      uint2 u; u.x = lo; u.y = hi;
      *(uint2*)&Psh[(((wave * 16 + cl) * 64) + nt * 16 + g * 4) ^ ((cl & 7) << 3)] = u;
    }

    // O += P V, lsum += P * ones : A = P (rows q), B = V^T (rows d) / ones
    short8 pa[2];
    #pragma unroll
    for (int kk = 0; kk < 2; ++kk)
      pa[kk] = *(const short8*)&Psh[(((wave * 16 + cl) * 64) + kk * 32 + g * 8)
                                    ^ ((cl & 7) << 3)];
    __builtin_amdgcn_s_setprio(1);
    #pragma unroll
    for (int kk = 0; kk < 2; ++kk) {
      #pragma unroll
      for (int dt = 0; dt < 4; ++dt) {
        short8 bv = *(const short8*)&Vsh[buf][(dt * 16 + cl) * 64
                                             + ((kk * 32 + g * 8) ^ ((cl & 7) << 3))];
        oacc[dt] = __builtin_amdgcn_mfma_f32_16x16x32_bf16(pa[kk], bv, oacc[dt], 0, 0, 0);
      }
      lsum = __builtin_amdgcn_mfma_f32_16x16x32_bf16(pa[kk], ones, lsum, 0, 0, 0);
    }
    __builtin_amdgcn_s_setprio(0);

    __syncthreads();   // drains vmcnt (next tile staged) + protects buffer reuse
    buf ^= 1;
  }

  // epilogue: lsum[r] is the row-sum for q = qb + g*4 + r (col-replicated)
  #pragma unroll
  for (int r = 0; r < 4; ++r) {
    float iv = __builtin_amdgcn_rcpf(lsum[r]);
    #pragma unroll
    for (int dt = 0; dt < 4; ++dt)
      ctx[baseq + (size_t)(qb + g * 4 + r) * D_ + dt * 16 + cl] = f2bf(oacc[dt][r] * iv);
  }
#undef STAGE_KV
}

// ---------------- launch ----------------
extern "C" void kernel_launch(void* const* d_in, const int* in_sizes, int n_in,
                              void* d_out, int out_size, void* d_ws, size_t ws_size,
                              hipStream_t stream) {
  (void)in_sizes; (void)n_in; (void)out_size; (void)ws_size;
  const float* q    = (const float*)d_in[0];
  const float* k    = (const float*)d_in[1];
  const float* v    = (const float*)d_in[2];
  const int*   mask = (const int*)d_in[3];
  const float* Wq   = (const float*)d_in[4];
  const float* bq   = (const float*)d_in[5];
  const float* Wk   = (const float*)d_in[6];
  const float* bk   = (const float*)d_in[7];
  const float* Wv   = (const float*)d_in[8];
  const float* bv   = (const float*)d_in[9];
  const float* Wo   = (const float*)d_in[10];
  const float* bo   = (const float*)d_in[11];

  char* ws = (char*)d_ws;
  const size_t MB = 1024 * 1024;
  unsigned short* Wqb  = (unsigned short*)(ws + 16 * MB);
  unsigned short* Wkb  = (unsigned short*)(ws + 18 * MB);
  unsigned short* Wvb  = (unsigned short*)(ws + 20 * MB);
  unsigned short* Wob  = (unsigned short*)(ws + 22 * MB);
  unsigned short* qwb  = (unsigned short*)(ws + 24 * MB);  // pre-scaled Q proj
  unsigned short* kwb  = (unsigned short*)(ws + 40 * MB);
  unsigned short* vtb  = (unsigned short*)(ws + 56 * MB);  // V^T per head
  unsigned short* ctx  = (unsigned short*)(ws + 72 * MB);
  unsigned long long* mwd = (unsigned long long*)(ws + 88 * MB);  // 512 KB

  const int NW = D_ * D_;

  cast4_bf16<<<dim3(512, 4), 256, 0, stream>>>(Wq, Wk, Wv, Wo, Wqb, Wkb, Wvb, Wob, NW);
  mask_pack2<<<1024, 256, 0, stream>>>(mask, mwd);

  dim3 gproj(64, 8);       // (B*L)/128 x D/128
  dim3 gproj2(64, 8, 2);   // fused q+k projections

  // Q pre-scaled by log2e / sqrt(HD) for log2-domain softmax
  const float QSCALE = 0.125f * 1.44269504088896340736f;

  // fused q+k projection (z=0 -> q, z=1 -> k)
  gemm_bt<1, true, true><<<gproj2, 256, 0, stream>>>(
      q, k, Wqb, Wkb, bq, bk, qwb, kwb, QSCALE, 1.0f, D_);
  // v projection with per-head transpose epilogue
  gemm_bt<2, true, false><<<gproj, 256, 0, stream>>>(
      v, v, Wvb, Wvb, bv, bv, vtb, vtb, 1.0f, 1.0f, D_);

  flash_attn<<<dim3(2048), 256, 0, stream>>>(qwb, kwb, vtb, mwd, ctx);

  // output projection (f32 out)
  gemm_bt<0, false, false><<<gproj, 256, 0, stream>>>(
      ctx, ctx, Wob, Wob, bo, bo, d_out, d_out, 1.0f, 1.0f, D_);
}